// Round 6
// baseline (1047.887 us; speedup 1.0000x reference)
//
#include <hip/hip_runtime.h>
#include <hip/hip_bf16.h>
#include <stdint.h>

// FusedLinearCrossEntropyLoss on MI355X (gfx950)
// loss = mean_i( logsumexp_j(x_i . w_j + b_j) - (x_i . w_t(i) + b_t(i)) )
//
// R11: R6 no-LDS loop + PARTIAL register double-buffer (fits the reg file).
//      Diagnosis recap: kg period ~3190cy vs 552cy MFMA/wave at 2 waves/SIMD;
//      VGPR=84 => zero operand lookahead, each kg exposes ~600cy L3 latency.
//      R9's full 2-deep buffer (demand ~246 regs) spilled (WRITE 1GB).
//      Dose that fits: ping-pong stage {a0,a1,b0,b1} (2 sets x 32 regs),
//      a2,a3 single-buffered + reissued right after last use; MFMAs ordered
//      staged-first so the tail pair's latency hides under 414cy of MFMA.
//      Demand ~= 128 acc + 80 staged + ~25 addr = 233 <= 256.
//      Also: R9's contiguous 32B/lane chunk layout (proven correct, absmax 0)
//      -> fragment = 2 adjacent dwordx4, no repack movs.
//      R10's XCD remap reverted (measured byte-identical FETCH).
//
// Chunk layout: chunk c = R*16 + g (R = 32-row block, g = 64-wide k group).
// Within chunk: lane l in 0..63, byte b in 0..31:
//   data[c*2048 + l*32 + b] = M[R*32 + (l&31)][g*64 + (l>>5)*32 + b]

typedef float f16v __attribute__((ext_vector_type(16)));
typedef int v8i __attribute__((ext_vector_type(8)));
typedef int v4i __attribute__((ext_vector_type(4)));

__device__ __forceinline__ unsigned pk_fp8(float4 v) {
  int w = 0;
  w = __builtin_amdgcn_cvt_pk_fp8_f32(v.x, v.y, w, false);  // bytes 0,1
  w = __builtin_amdgcn_cvt_pk_fp8_f32(v.z, v.w, w, true);   // bytes 2,3
  return (unsigned)w;
}

// fp32 [N x 1024] -> fp8 fragment-swizzled chunks (contiguous 32B/lane).
// One thread = 16 out bytes. (Verified correct in R9: absmax 0.)
__global__ __launch_bounds__(256) void cast_swz_k(const float* __restrict__ in,
                                                  uint4* __restrict__ out,
                                                  long n16) {
  long t = (long)blockIdx.x * blockDim.x + threadIdx.x;
  long stride = (long)gridDim.x * blockDim.x;
  for (; t < n16; t += stride) {
    long o = t * 16;
    int c = (int)(o >> 11);
    int rem = (int)(o & 2047);
    int l = rem >> 5;            // lane
    int b0 = rem & 31;           // 0 or 16
    int row = (c >> 4) * 32 + (l & 31);
    int k = (c & 15) * 64 + (l >> 5) * 32 + b0;
    const float4* src = (const float4*)(in + (long)row * 1024 + k);
    uint4 oo;
    oo.x = pk_fp8(src[0]); oo.y = pk_fp8(src[1]);
    oo.z = pk_fp8(src[2]); oo.w = pk_fp8(src[3]);
    out[t] = oo;
  }
}

// One block per row: x_y[row] = x[row] . W[safe_t] + bias[safe_t]  (fp32, exact)
__global__ __launch_bounds__(256) void xy_k(const float* __restrict__ x,
                                            const float* __restrict__ w,
                                            const float* __restrict__ bias,
                                            const int* __restrict__ tgt,
                                            float* __restrict__ xy, int H, int V) {
  int row = blockIdx.x;
  int t = tgt[row];
  int st = min(max(t, 0), V - 1);
  const float4* xr = (const float4*)(x + (long)row * H);
  const float4* wr = (const float4*)(w + (long)st * H);
  float s = 0.f;
  int n4 = H >> 2;
  for (int i = threadIdx.x; i < n4; i += 256) {
    float4 a = xr[i], b = wr[i];
    s += a.x * b.x + a.y * b.y + a.z * b.z + a.w * b.w;
  }
  for (int off = 32; off; off >>= 1) s += __shfl_down(s, off, 64);
  __shared__ float sm[4];
  if ((threadIdx.x & 63) == 0) sm[threadIdx.x >> 6] = s;
  __syncthreads();
  if (threadIdx.x == 0) xy[row] = sm[0] + sm[1] + sm[2] + sm[3] + bias[st];
}

// Load one 32B/lane fragment (two adjacent dwordx4 -> v8i, no repack).
__device__ __forceinline__ v8i ldfrag(const char* p) {
  const v4i* q = (const v4i*)p;
  v4i lo = q[0];
  v4i hi = q[1];
  return __builtin_shufflevector(lo, hi, 0, 1, 2, 3, 4, 5, 6, 7);
}

#define MFMA1(A, B, C) \
  __builtin_amdgcn_mfma_scale_f32_32x32x64_f8f6f4(A, B, C, 0, 0, 0, 127, 0, 127)

// 256x128 block tile, 4 waves in 2x2; each wave 128x64 via 4x2 of 32x32x64.
// No LDS; partial register double-buffer (see header comment).
// Epilogue: partials[by][row] = sum_cols exp(logit + bias).
__global__ __launch_bounds__(256, 2)
void gemm_sumexp(const char* __restrict__ Xf, const char* __restrict__ Wf,
                 const float* __restrict__ bias, float* __restrict__ partials,
                 int H, int BT) {
  __shared__ float rowsum[2][256];

  const int tid = threadIdx.x;
  const int w = tid >> 6, lane = tid & 63;
  const int wr = w >> 1, wc = w & 1;
  const int l32 = lane & 31, kh = lane >> 5;

  const int bx = blockIdx.x;   // row-blocks fast-varying (W tile L2 sharing)
  const int by = blockIdx.y;
  const int m0 = bx * 256, n0 = by * 128;

  const int Rb = bx * 8 + wr * 4;   // A 32-row block base
  const int Nb = by * 4 + wc * 2;   // B 32-row block base

  const char* pA0 = Xf + (long)(Rb + 0) * 32768 + lane * 32;
  const char* pA1 = Xf + (long)(Rb + 1) * 32768 + lane * 32;
  const char* pA2 = Xf + (long)(Rb + 2) * 32768 + lane * 32;
  const char* pA3 = Xf + (long)(Rb + 3) * 32768 + lane * 32;
  const char* pB0 = Wf + (long)(Nb + 0) * 32768 + lane * 32;
  const char* pB1 = Wf + (long)(Nb + 1) * 32768 + lane * 32;

  f16v acc[4][2];
#pragma unroll
  for (int mi = 0; mi < 4; mi++)
#pragma unroll
    for (int ni = 0; ni < 2; ni++)
#pragma unroll
      for (int r = 0; r < 16; r++) acc[mi][ni][r] = 0.f;

  const int nG = H >> 6;  // 16 k-groups of 64 (even, >= 4)

  // Staged ping-pong sets: S (even kgs) / T (odd kgs); tail a2,a3 shared.
  v8i sA0, sA1, sB0, sB1, tA0, tA1, tB0, tB1, a2, a3;
  sA0 = ldfrag(pA0);        sA1 = ldfrag(pA1);
  sB0 = ldfrag(pB0);        sB1 = ldfrag(pB1);
  a2  = ldfrag(pA2);        a3  = ldfrag(pA3);
  tA0 = ldfrag(pA0 + 2048); tA1 = ldfrag(pA1 + 2048);
  tB0 = ldfrag(pB0 + 2048); tB1 = ldfrag(pB1 + 2048);

  // Section for one kg: staged-first MFMA order; tail pair reissued right
  // after its last use; staged set refilled (for kg+2) at section end.
#define SECTION(SA0, SA1, SB0, SB1, TAILOFF, SOFF, DO_TAIL, DO_S)             \
  {                                                                           \
    acc[0][0] = MFMA1(SA0, SB0, acc[0][0]);                                   \
    acc[0][1] = MFMA1(SA0, SB1, acc[0][1]);                                   \
    acc[1][0] = MFMA1(SA1, SB0, acc[1][0]);                                   \
    acc[1][1] = MFMA1(SA1, SB1, acc[1][1]);                                   \
    acc[2][0] = MFMA1(a2, SB0, acc[2][0]);                                    \
    acc[2][1] = MFMA1(a2, SB1, acc[2][1]);                                    \
    if (DO_TAIL) a2 = ldfrag(pA2 + (TAILOFF));                                \
    acc[3][0] = MFMA1(a3, SB0, acc[3][0]);                                    \
    acc[3][1] = MFMA1(a3, SB1, acc[3][1]);                                    \
    if (DO_TAIL) a3 = ldfrag(pA3 + (TAILOFF));                                \
    if (DO_S) {                                                               \
      SA0 = ldfrag(pA0 + (SOFF)); SA1 = ldfrag(pA1 + (SOFF));                 \
      SB0 = ldfrag(pB0 + (SOFF)); SB1 = ldfrag(pB1 + (SOFF));                 \
    }                                                                         \
  }

#pragma unroll 1
  for (int g = 0; g + 2 <= nG; g += 2) {
    const long o1 = (long)(g + 1) * 2048;
    const long o2 = (long)(g + 2) * 2048;
    const long o3 = (long)(g + 3) * 2048;
    const bool h2 = (g + 2 < nG), h3 = (g + 3 < nG);
    // even kg g: consume S set
    SECTION(sA0, sA1, sB0, sB1, o1, o2, true, h2)
    // odd kg g+1: consume T set
    SECTION(tA0, tA1, tB0, tB1, o2, o3, h2, h3)
  }
#undef SECTION

  // ---- epilogue: per-row sum of exp(logit + bias) ----
  // C/D 32x32 layout: col = lane&31, row = (reg&3) + 8*(reg>>2) + 4*(lane>>5)
  float bv[2];
  bv[0] = bias[n0 + wc * 64 + l32];
  bv[1] = bias[n0 + wc * 64 + 32 + l32];

#pragma unroll
  for (int mi = 0; mi < 4; mi++) {
    float p[16];
#pragma unroll
    for (int r = 0; r < 16; r++) p[r] = 0.f;
#pragma unroll
    for (int ni = 0; ni < 2; ni++)
#pragma unroll
      for (int r = 0; r < 16; r++) p[r] += __expf(acc[mi][ni][r] + bv[ni]);
    // reduce across the 32 columns (lanes within each 32-group)
#pragma unroll
    for (int off = 1; off < 32; off <<= 1)
#pragma unroll
      for (int r = 0; r < 16; r++) p[r] += __shfl_xor(p[r], off, 32);
    if (l32 == 0) {
#pragma unroll
      for (int r = 0; r < 16; r++)
        rowsum[wc][wr * 128 + mi * 32 + (r & 3) + 8 * (r >> 2) + 4 * kh] = p[r];
    }
  }
  __syncthreads();
  partials[(long)by * BT + m0 + tid] = rowsum[0][tid] + rowsum[1][tid];
}

// per-row: lse - x_y ; 4 threads per row for b-parallelism, 64 rows/block
__global__ __launch_bounds__(256)
void row_reduce(const float* __restrict__ partials, const float* __restrict__ xy,
                const int* __restrict__ tgt, float* __restrict__ bsum,
                float* __restrict__ bcnt, int BT, int nCB) {
  const int row = blockIdx.x * 64 + (threadIdx.x >> 2);
  const int q = threadIdx.x & 3;
  float S = 0.f;
  for (int b = q; b < nCB; b += 4) S += partials[(long)b * BT + row];
  S += __shfl_xor(S, 1, 64);
  S += __shfl_xor(S, 2, 64);
  float pr = 0.f, c = 0.f;
  if (q == 0) {
    int t = tgt[row];
    if (t != -100) { pr = logf(S) - xy[row]; c = 1.f; }
  }
  for (int off = 32; off; off >>= 1) {
    pr += __shfl_down(pr, off, 64);
    c += __shfl_down(c, off, 64);
  }
  __shared__ float sp[4], sc[4];
  if ((threadIdx.x & 63) == 0) {
    sp[threadIdx.x >> 6] = pr;
    sc[threadIdx.x >> 6] = c;
  }
  __syncthreads();
  if (threadIdx.x == 0) {
    bsum[blockIdx.x] = sp[0] + sp[1] + sp[2] + sp[3];
    bcnt[blockIdx.x] = sc[0] + sc[1] + sc[2] + sc[3];
  }
}

__global__ void finalize(const float* __restrict__ bsum, const float* __restrict__ bcnt,
                         float* __restrict__ out, int nb) {
  float s = 0.f, c = 0.f;
  for (int i = threadIdx.x; i < nb; i += 64) { s += bsum[i]; c += bcnt[i]; }
  for (int off = 32; off; off >>= 1) {
    s += __shfl_down(s, off, 64);
    c += __shfl_down(c, off, 64);
  }
  if (threadIdx.x == 0) out[0] = s / c;
}

extern "C" void kernel_launch(void* const* d_in, const int* in_sizes, int n_in,
                              void* d_out, int out_size, void* d_ws, size_t ws_size,
                              hipStream_t stream) {
  const float* x = (const float*)d_in[0];
  const int* tgt = (const int*)d_in[1];
  const float* w = (const float*)d_in[2];
  const float* bias = (const float*)d_in[3];
  float* out = (float*)d_out;

  const int BT = in_sizes[1];            // 4096
  const int V = in_sizes[3];             // 32000
  const int H = in_sizes[0] / BT;        // 1024
  const int nCB = V / 128;               // 250 column blocks

  char* ws = (char*)d_ws;
  const long wb_bytes = (long)V * H;     // fp8: 1 B/elem
  const long xb_bytes = (long)BT * H;
  char* Wf = ws;
  char* Xf = ws + wb_bytes;
  float* partials = (float*)(ws + wb_bytes + xb_bytes);
  float* xy = partials + (long)nCB * BT;
  float* bsum = xy + BT;
  float* bcnt = bsum + (BT / 64);

  cast_swz_k<<<8192, 256, 0, stream>>>(w, (uint4*)Wf, (long)V * H / 16);
  cast_swz_k<<<1024, 256, 0, stream>>>(x, (uint4*)Xf, (long)BT * H / 16);
  xy_k<<<BT, 256, 0, stream>>>(x, w, bias, tgt, xy, H, V);
  // grid.x = row-blocks (fast-varying) so consecutive blocks share the W tile in L2
  dim3 grid(BT / 256, nCB);
  gemm_sumexp<<<grid, 256, 0, stream>>>(Xf, Wf, bias, partials, H, BT);
  row_reduce<<<BT / 64, 256, 0, stream>>>(partials, xy, tgt, bsum, bcnt, BT, nCB);
  finalize<<<1, 64, 0, stream>>>(bsum, bcnt, out, BT / 64);
}

// Round 8
// 372.543 us; speedup vs baseline: 2.8128x; 2.8128x over previous
//
#include <hip/hip_runtime.h>
#include <hip/hip_bf16.h>
#include <stdint.h>

// FusedLinearCrossEntropyLoss on MI355X (gfx950)
// loss = mean_i( logsumexp_j(x_i . w_j + b_j) - (x_i . w_t(i) + b_t(i)) )
//
// R12 (resubmit; round 7 was a broker timeout, no data):
//      OCCUPANCY instead of register pipelining.
//      R9/R11 proved: with 128 acc regs, any multi-set operand staging spills
//      (WRITE_SIZE 1-2.8 GB). So hide latency with MORE WAVES instead:
//      per-wave tile 64x64 (acc 64 regs, ops 32, addr ~25 -> ~125-150 demand),
//      __launch_bounds__(256,3) -> 170-reg cap, 3 waves/SIMD (R6: 2).
//      Block = 128x128 (4 waves 2x2), grid 32x250. No LDS, no barriers,
//      single operand set per kg (the only structure that hasn't spilled).
//      Also: -2 launches (merged casts; xy fused into row_reduce).
//
// Chunk layout: chunk c = R*16 + g (R = 32-row block, g = 64-wide k group).
// Within chunk: lane l in 0..63, byte b in 0..31:
//   data[c*2048 + l*32 + b] = M[R*32 + (l&31)][g*64 + (l>>5)*32 + b]

typedef float f16v __attribute__((ext_vector_type(16)));
typedef int v8i __attribute__((ext_vector_type(8)));
typedef int v4i __attribute__((ext_vector_type(4)));

__device__ __forceinline__ unsigned pk_fp8(float4 v) {
  int w = 0;
  w = __builtin_amdgcn_cvt_pk_fp8_f32(v.x, v.y, w, false);  // bytes 0,1
  w = __builtin_amdgcn_cvt_pk_fp8_f32(v.z, v.w, w, true);   // bytes 2,3
  return (unsigned)w;
}

// fp32 [N x 1024] -> fp8 fragment-swizzled chunks (contiguous 32B/lane).
// One kernel handles BOTH W and X (fewer launches). One thread = 16 out bytes.
__global__ __launch_bounds__(256) void cast_swz2_k(const float* __restrict__ inW,
                                                   uint4* __restrict__ outW,
                                                   const float* __restrict__ inX,
                                                   uint4* __restrict__ outX,
                                                   long nW16, long nX16) {
  long t = (long)blockIdx.x * blockDim.x + threadIdx.x;
  long stride = (long)gridDim.x * blockDim.x;
  long total = nW16 + nX16;
  for (; t < total; t += stride) {
    const float* in;
    uint4* out;
    long i;
    if (t < nW16) { in = inW; out = outW; i = t; }
    else          { in = inX; out = outX; i = t - nW16; }
    long o = i * 16;
    int c = (int)(o >> 11);
    int rem = (int)(o & 2047);
    int l = rem >> 5;            // lane
    int b0 = rem & 31;           // 0 or 16
    int row = (c >> 4) * 32 + (l & 31);
    int k = (c & 15) * 64 + (l >> 5) * 32 + b0;
    const float4* src = (const float4*)(in + (long)row * 1024 + k);
    uint4 oo;
    oo.x = pk_fp8(src[0]); oo.y = pk_fp8(src[1]);
    oo.z = pk_fp8(src[2]); oo.w = pk_fp8(src[3]);
    out[i] = oo;
  }
}

// Load one 32B/lane fragment (two adjacent dwordx4 -> v8i).
__device__ __forceinline__ v8i ldfrag(const char* p) {
  const v4i* q = (const v4i*)p;
  v4i lo = q[0];
  v4i hi = q[1];
  return __builtin_shufflevector(lo, hi, 0, 1, 2, 3, 4, 5, 6, 7);
}

#define MFMA1(A, B, C) \
  __builtin_amdgcn_mfma_scale_f32_32x32x64_f8f6f4(A, B, C, 0, 0, 0, 127, 0, 127)

// 128x128 block tile, 4 waves in 2x2; each wave 64x64 via 2x2 of 32x32x64.
// No LDS staging, no barriers in the K-loop, one operand set live.
// Epilogue: partials[by][row] = sum over this 128-col panel of exp(logit+bias).
__global__ __launch_bounds__(256, 3)
void gemm_sumexp(const char* __restrict__ Xf, const char* __restrict__ Wf,
                 const float* __restrict__ bias, float* __restrict__ partials,
                 int H, int BT) {
  __shared__ float rowsum[2][128];

  const int tid = threadIdx.x;
  const int w = tid >> 6, lane = tid & 63;
  const int wr = w >> 1, wc = w & 1;
  const int l32 = lane & 31, kh = lane >> 5;

  const int bx = blockIdx.x;   // row-blocks fast-varying (W panel L2 sharing)
  const int by = blockIdx.y;
  const int m0 = bx * 128, n0 = by * 128;

  const int Rb = bx * 4 + wr * 2;   // A 32-row block base
  const int Nb = by * 4 + wc * 2;   // B 32-row block base

  const char* pA0 = Xf + (long)(Rb + 0) * 32768 + lane * 32;
  const char* pA1 = Xf + (long)(Rb + 1) * 32768 + lane * 32;
  const char* pB0 = Wf + (long)(Nb + 0) * 32768 + lane * 32;
  const char* pB1 = Wf + (long)(Nb + 1) * 32768 + lane * 32;

  f16v acc[2][2];
#pragma unroll
  for (int mi = 0; mi < 2; mi++)
#pragma unroll
    for (int ni = 0; ni < 2; ni++)
#pragma unroll
      for (int r = 0; r < 16; r++) acc[mi][ni][r] = 0.f;

  const int nG = H >> 6;  // 16 k-groups of 64
#pragma unroll 4
  for (int g = 0; g < nG; g++) {
    v8i a0 = ldfrag(pA0); pA0 += 2048;
    v8i a1 = ldfrag(pA1); pA1 += 2048;
    v8i b0 = ldfrag(pB0); pB0 += 2048;
    v8i b1 = ldfrag(pB1); pB1 += 2048;
    acc[0][0] = MFMA1(a0, b0, acc[0][0]);
    acc[0][1] = MFMA1(a0, b1, acc[0][1]);
    acc[1][0] = MFMA1(a1, b0, acc[1][0]);
    acc[1][1] = MFMA1(a1, b1, acc[1][1]);
  }

  // ---- epilogue: per-row sum of exp(logit + bias) ----
  // C/D 32x32 layout: col = lane&31, row = (reg&3) + 8*(reg>>2) + 4*(lane>>5)
  float bv[2];
  bv[0] = bias[n0 + wc * 64 + l32];
  bv[1] = bias[n0 + wc * 64 + 32 + l32];

#pragma unroll
  for (int mi = 0; mi < 2; mi++) {
    float p[16];
#pragma unroll
    for (int r = 0; r < 16; r++) p[r] = 0.f;
#pragma unroll
    for (int ni = 0; ni < 2; ni++)
#pragma unroll
      for (int r = 0; r < 16; r++) p[r] += __expf(acc[mi][ni][r] + bv[ni]);
    // reduce across the 32 columns (lanes within each 32-group)
#pragma unroll
    for (int off = 1; off < 32; off <<= 1)
#pragma unroll
      for (int r = 0; r < 16; r++) p[r] += __shfl_xor(p[r], off, 32);
    if (l32 == 0) {
#pragma unroll
      for (int r = 0; r < 16; r++)
        rowsum[wc][wr * 64 + mi * 32 + (r & 3) + 8 * (r >> 2) + 4 * kh] = p[r];
    }
  }
  __syncthreads();
  if (tid < 128)
    partials[(long)by * BT + m0 + tid] = rowsum[0][tid] + rowsum[1][tid];
}

// Fused per-row finish: S = sum of panel partials; x_y = x[row].W[t] + b[t]
// (exact fp32, was xy_k); pr = log(S) - x_y. One wave per row.
__global__ __launch_bounds__(256)
void row_reduce(const float* __restrict__ partials, const float* __restrict__ x,
                const float* __restrict__ wt, const float* __restrict__ bias,
                const int* __restrict__ tgt, float* __restrict__ bsum,
                float* __restrict__ bcnt, int BT, int nCB, int H, int V) {
  const int w = threadIdx.x >> 6, lane = threadIdx.x & 63;
  const int row = blockIdx.x * 4 + w;
  float S = 0.f;
  for (int b = lane; b < nCB; b += 64) S += partials[(long)b * BT + row];
  const int t = tgt[row];
  const int st = min(max(t, 0), V - 1);
  const float4* xr = (const float4*)(x + (long)row * H);
  const float4* wr = (const float4*)(wt + (long)st * H);
  float d = 0.f;
  const int n4 = H >> 2;
  for (int i = lane; i < n4; i += 64) {
    float4 a = xr[i], b = wr[i];
    d += a.x * b.x + a.y * b.y + a.z * b.z + a.w * b.w;
  }
  for (int off = 32; off; off >>= 1) {
    S += __shfl_down(S, off, 64);
    d += __shfl_down(d, off, 64);
  }
  __shared__ float sp[4], sc[4];
  if (lane == 0) {
    bool valid = (t != -100);
    sp[w] = valid ? (logf(S) - (d + bias[st])) : 0.f;
    sc[w] = valid ? 1.f : 0.f;
  }
  __syncthreads();
  if (threadIdx.x == 0) {
    bsum[blockIdx.x] = sp[0] + sp[1] + sp[2] + sp[3];
    bcnt[blockIdx.x] = sc[0] + sc[1] + sc[2] + sc[3];
  }
}

__global__ void finalize(const float* __restrict__ bsum, const float* __restrict__ bcnt,
                         float* __restrict__ out, int nb) {
  float s = 0.f, c = 0.f;
  for (int i = threadIdx.x; i < nb; i += 64) { s += bsum[i]; c += bcnt[i]; }
  for (int off = 32; off; off >>= 1) {
    s += __shfl_down(s, off, 64);
    c += __shfl_down(c, off, 64);
  }
  if (threadIdx.x == 0) out[0] = s / c;
}

extern "C" void kernel_launch(void* const* d_in, const int* in_sizes, int n_in,
                              void* d_out, int out_size, void* d_ws, size_t ws_size,
                              hipStream_t stream) {
  const float* x = (const float*)d_in[0];
  const int* tgt = (const int*)d_in[1];
  const float* w = (const float*)d_in[2];
  const float* bias = (const float*)d_in[3];
  float* out = (float*)d_out;

  const int BT = in_sizes[1];            // 4096
  const int V = in_sizes[3];             // 32000
  const int H = in_sizes[0] / BT;        // 1024
  const int nCB = V / 128;               // 250 column panels

  char* ws = (char*)d_ws;
  const long wb_bytes = (long)V * H;     // fp8: 1 B/elem
  const long xb_bytes = (long)BT * H;
  char* Wf = ws;
  char* Xf = ws + wb_bytes;
  float* partials = (float*)(ws + wb_bytes + xb_bytes);
  float* bsum = partials + (long)nCB * BT;
  float* bcnt = bsum + (BT / 4);

  cast_swz2_k<<<9024, 256, 0, stream>>>(w, (uint4*)Wf, x, (uint4*)Xf,
                                        (long)V * H / 16, (long)BT * H / 16);
  dim3 grid(BT / 128, nCB);
  gemm_sumexp<<<grid, 256, 0, stream>>>(Xf, Wf, bias, partials, H, BT);
  row_reduce<<<BT / 4, 256, 0, stream>>>(partials, x, w, bias, tgt, bsum, bcnt,
                                         BT, nCB, H, V);
  finalize<<<1, 64, 0, stream>>>(bsum, bcnt, out, BT / 4);
}